// Round 11
// baseline (140.011 us; speedup 1.0000x reference)
//
#include <hip/hip_runtime.h>
#include <hip/hip_bf16.h>
#include <math.h>

#define B_   64
#define S_   8
#define T_   8192
#define T3_  8166      // 8192 - 26
#define T3P  8168      // padded row stride
#define EPS_ 1e-8f
#define SWZ8(r) ((((r) >> 2) & 1) << 3)   // half-swizzle: XOR of the 16B-half by row bit 2

typedef __bf16 bf16x8 __attribute__((ext_vector_type(8)));
typedef float  f32x4  __attribute__((ext_vector_type(4)));

__device__ __forceinline__ unsigned short f2bf(float x) {
    __hip_bfloat16 h = __float2bfloat16(x);
    return *reinterpret_cast<unsigned short*>(&h);
}
__device__ __forceinline__ unsigned int pk2(float a, float b) {
    return (unsigned int)f2bf(a) | ((unsigned int)f2bf(b) << 16);
}
__device__ __forceinline__ bf16x8 as_bf(uint4 u) { return *reinterpret_cast<bf16x8*>(&u); }

// =========== KA: streaming 1x1 conv 64->8 + (block 0) weight-fragment pack ===========
__global__ __launch_bounds__(256) void k_eeg1x1(const float* __restrict__ eeg,
                                                const float* __restrict__ w,
                                                const float* __restrict__ bias,
                                                unsigned short* __restrict__ x0b,
        const float* __restrict__ w_e1, const float* __restrict__ w_e2, const float* __restrict__ w_e3,
        const float* __restrict__ w_s2, const float* __restrict__ w_s3,
        unsigned short* __restrict__ wfE, unsigned short* __restrict__ wfS) {
    __shared__ float ws[512];
    __shared__ float bs[8];
    int tid = threadIdx.x;

    if (blockIdx.x == 0) {   // ---- pack MFMA weight fragments (bf16) ----
        for (int idx = tid; idx < 2560; idx += 256) {
            int arr = idx >> 9, e = idx & 511;
            int m = e >> 5, k5 = e & 31;
            float v = 0.f;
            if (arr == 0)      { int tap = k5 >> 3, ci = k5 & 7; if (tap < 3) v = w_e1[(m * 8 + ci) * 3 + tap]; }
            else if (arr == 1) { int tap = k5 >> 4, ci = k5 & 15; v = w_e2[(m * 16 + ci) * 3 + tap]; }
            else if (arr == 2) { if (k5 < 16) v = w_e2[(m * 16 + k5) * 3 + 2]; }
            else if (arr == 3) { int tap = k5 >> 4, ci = k5 & 15; v = w_e3[(m * 16 + ci) * 3 + tap]; }
            else               { if (k5 < 16) v = w_e3[(m * 16 + k5) * 3 + 2]; }
            wfE[idx] = f2bf(v);
        }
        for (int idx = tid; idx < 2048; idx += 256) {
            int arr = idx >> 9, e = idx & 511;
            int m = e >> 5, k5 = e & 31;
            int ci = k5 & 15, tap = k5 >> 4;
            float v;
            if (arr == 0)      v = w_s2[(m * 16 + ci) * 3 + tap];
            else if (arr == 1) v = (k5 < 16) ? w_s2[(m * 16 + k5) * 3 + 2] : 0.f;
            else if (arr == 2) v = w_s3[(m * 16 + ci) * 3 + tap];
            else               v = (k5 < 16) ? w_s3[(m * 16 + k5) * 3 + 2] : 0.f;
            wfS[idx] = f2bf(v);
        }
    }

    ws[tid]       = w[tid];
    ws[tid + 256] = w[tid + 256];
    if (tid < 8) bs[tid] = bias[tid];
    __syncthreads();

    int gt = blockIdx.x * 256 + tid;
    const float* ep = eeg + (size_t)gt * 64;

    float acc[8];
#pragma unroll
    for (int c = 0; c < 8; ++c) acc[c] = bs[c];
#pragma unroll
    for (int i = 0; i < 64; i += 4) {
        float4 v = *(const float4*)(ep + i);
#pragma unroll
        for (int c = 0; c < 8; ++c) {
            const float* wp = ws + c * 64 + i;
            acc[c] += v.x * wp[0] + v.y * wp[1] + v.z * wp[2] + v.w * wp[3];
        }
    }
    uint4 p = { pk2(acc[0], acc[1]), pk2(acc[2], acc[3]),
                pk2(acc[4], acc[5]), pk2(acc[6], acc[7]) };
    *(uint4*)(x0b + (size_t)gt * 8) = p;
}

// =========== KB: eeg dilated stack, unrolled const-offset MFMA (R9/R10-verified) ===========
__global__ __launch_bounds__(256) void k_estack(const unsigned short* __restrict__ x0b,
        const float* __restrict__ b1, const float* __restrict__ b2, const float* __restrict__ b3,
        const unsigned short* __restrict__ wfE,
        unsigned short* __restrict__ x3b, float* __restrict__ nxp) {
    __shared__ __align__(16) unsigned char smem[24064];
    unsigned short* x0T = (unsigned short*)smem;
    unsigned short* i1  = (unsigned short*)(smem + 4864);
    unsigned short* i2  = (unsigned short*)(smem + 14592);
    float*          wred= (float*)(smem + 23808);
    unsigned short* st3 = (unsigned short*)smem;

    int tid = threadIdx.x;
    int chunk = blockIdx.x, b = blockIdx.y;
    int wv = tid >> 6, lane = tid & 63, lm = lane & 15, lg = lane >> 4;

    int c0 = chunk * 256;
    int Lv = min(256, T3_ - c0);
    int n_in = Lv + 26, n1 = Lv + 24;

    {
        const unsigned short* src = x0b + ((size_t)b * T_ + c0) * 8;
        uint4 z = {0, 0, 0, 0};
        for (int r = tid; r < 304; r += 256) {
            uint4 v = (r < n_in) ? *(const uint4*)(src + r * 8) : z;
            *(uint4*)(x0T + r * 8) = v;
        }
    }
    for (int idx = tid; idx < (304 - n1) * 8; idx += 256)
        ((unsigned int*)(i1 + n1 * 16))[idx] = 0;
    __syncthreads();

    const bf16x8 W1f = *(const bf16x8*)(wfE +         lm * 32 + 8 * lg);
    const bf16x8 W2a = *(const bf16x8*)(wfE + 512  +  lm * 32 + 8 * lg);
    const bf16x8 W2b = *(const bf16x8*)(wfE + 1024 +  lm * 32 + 8 * lg);
    const bf16x8 W3a = *(const bf16x8*)(wfE + 1536 +  lm * 32 + 8 * lg);
    const bf16x8 W3b = *(const bf16x8*)(wfE + 2048 +  lm * 32 + 8 * lg);
    f32x4 c1v, c2v, c3v;
#pragma unroll
    for (int r = 0; r < 4; ++r) {
        c1v[r] = b1[4 * lg + r];
        c2v[r] = b2[4 * lg + r];
        c3v[r] = b3[lm];
    }

    int t0 = wv * 16 + lm;
    const unsigned short* px0 = x0T + (t0 + lg) * 8;
    unsigned short* pw1 = i1 + t0 * 16 + ((((lg >> 1) << 3) ^ SWZ8(t0)) + (lg & 1) * 4);
    int ra2 = t0 + 3 * (lg >> 1);
    const unsigned short* pa2 = i1 + ra2 * 16 + (((lg & 1) << 3) ^ SWZ8(ra2));
    const unsigned short* pb2 = i1 + (ra2 + 6) * 16 + (((lg & 1) << 3) ^ SWZ8(ra2 + 6));
    unsigned short* pw2 = i2 + t0 * 16 + ((((lg >> 1) << 3) ^ SWZ8(t0)) + (lg & 1) * 4);
    int ra3 = t0 + 9 * (lg >> 1);
    const unsigned short* pa3 = i2 + ra3 * 16 + (((lg & 1) << 3) ^ SWZ8(ra3));
    const unsigned short* pb3 = i2 + (ra3 + 18) * 16 + (((lg & 1) << 3) ^ SWZ8(ra3 + 18));
    unsigned short* ps3 = st3 + lm * 264 + wv * 16 + 4 * lg;

#pragma unroll
    for (int k = 0; k < 5; ++k) {
        if (k == 4 && wv >= 2) break;
        bf16x8 Ba = *(const bf16x8*)(px0 + 512 * k);
        f32x4 acc = __builtin_amdgcn_mfma_f32_16x16x32_bf16(W1f, Ba, c1v, 0, 0, 0);
        if (t0 + 64 * k < n1) {
            uint2 pq = { pk2(fmaxf(acc[0], 0.f), fmaxf(acc[1], 0.f)),
                         pk2(fmaxf(acc[2], 0.f), fmaxf(acc[3], 0.f)) };
            *(uint2*)(pw1 + 1024 * k) = pq;
        }
    }
    __syncthreads();

#pragma unroll
    for (int k = 0; k < 5; ++k) {
        if (k == 4 && wv >= 2) break;
        bf16x8 Ba = *(const bf16x8*)(pa2 + 1024 * k);
        bf16x8 Bb = *(const bf16x8*)(pb2 + 1024 * k);
        f32x4 acc = c2v;
        acc = __builtin_amdgcn_mfma_f32_16x16x32_bf16(W2a, Ba, acc, 0, 0, 0);
        acc = __builtin_amdgcn_mfma_f32_16x16x32_bf16(W2b, Bb, acc, 0, 0, 0);
        uint2 pq = { pk2(fmaxf(acc[0], 0.f), fmaxf(acc[1], 0.f)),
                     pk2(fmaxf(acc[2], 0.f), fmaxf(acc[3], 0.f)) };
        *(uint2*)(pw2 + 1024 * k) = pq;
    }
    __syncthreads();

    float nstc = 0.f;
#pragma unroll
    for (int k = 0; k < 4; ++k) {
        bf16x8 Aa = *(const bf16x8*)(pa3 + 1024 * k);
        bf16x8 Ab = *(const bf16x8*)(pb3 + 1024 * k);
        f32x4 acc = c3v;
        acc = __builtin_amdgcn_mfma_f32_16x16x32_bf16(Aa, W3a, acc, 0, 0, 0);
        acc = __builtin_amdgcn_mfma_f32_16x16x32_bf16(Ab, W3b, acc, 0, 0, 0);
        int u4 = wv * 16 + 4 * lg + 64 * k;
        float v[4];
#pragma unroll
        for (int r = 0; r < 4; ++r) {
            float x = ((u4 + r) < Lv) ? fmaxf(acc[r], 0.f) : 0.f;
            v[r] = x;
            nstc += x * x;
        }
        uint2 pq = { pk2(v[0], v[1]), pk2(v[2], v[3]) };
        *(uint2*)(ps3 + 64 * k) = pq;
    }
    nstc += __shfl_xor(nstc, 16);
    nstc += __shfl_xor(nstc, 32);
    if (lg == 0) wred[wv * 16 + lm] = nstc;
    __syncthreads();

    if (tid < 16) {
        float s = wred[tid] + wred[16 + tid] + wred[32 + tid] + wred[48 + tid];
        nxp[((size_t)b * 16 + tid) * 32 + chunk] = s;
    }
    {
        unsigned short* dst = x3b + (size_t)(b * 16) * T3P + c0;
        for (int idx = tid; idx < 16 * 32; idx += 256) {
            int co = idx >> 5, off = (idx & 31) * 8;
            if (off + 8 <= Lv)
                *(uint4*)(dst + (size_t)co * T3P + off) = *(const uint4*)(st3 + co * 264 + off);
            else
                for (int k = off; k < Lv; ++k) dst[(size_t)co * T3P + k] = st3[co * 264 + k];
        }
        if (chunk == 31 && tid < 16)
            *(unsigned int*)(x3b + (size_t)(b * 16 + tid) * T3P + T3_) = 0;
    }
}

// =========== K4: stim stack — wave-private 128-t bands, 1 barrier/chunk ===========
// grid (512 bs, 4 G). LDS: sinb[2][544]f32 @0 (4352) ; i1w 4x176x16u16 @4352 (22528) ;
// i2w 4x160x16u16 @26880 (20480) -> 47360. s3w [16][136]u16 aliases own i1w band.
__global__ __launch_bounds__(256, 3) void k_stim(const float* __restrict__ stim,
                                              const float* __restrict__ w1,
                                              const float* __restrict__ b1,
                                              const float* __restrict__ b2,
                                              const float* __restrict__ b3,
                                              const unsigned short* __restrict__ wfS,
                                              const unsigned short* __restrict__ x3b,
                                              float* __restrict__ dotp, float* __restrict__ nstp) {
    __shared__ __align__(16) unsigned char smem[47360];
    float* sinb = (float*)smem;   // [2][544]

    int tid  = threadIdx.x;
    int bs   = blockIdx.x;
    int G    = blockIdx.y;
    int wv   = tid >> 6;
    int lane = tid & 63;
    int lm   = lane & 15;
    int lg   = lane >> 4;
    int w0   = wv * 128;

    unsigned short* i1w = (unsigned short*)(smem + 4352  + wv * 5632);   // [176][16]
    unsigned short* i2w = (unsigned short*)(smem + 26880 + wv * 5120);   // [160][16]
    unsigned short* s3w = i1w;                                           // [16][136]

    const bf16x8 W2a = *(const bf16x8*)(wfS +         lm * 32 + 8 * lg);
    const bf16x8 W2b = *(const bf16x8*)(wfS + 512  +  lm * 32 + 8 * lg);
    const bf16x8 W3a = *(const bf16x8*)(wfS + 1024 +  lm * 32 + 8 * lg);
    const bf16x8 W3b = *(const bf16x8*)(wfS + 1536 +  lm * 32 + 8 * lg);
    f32x4 c2v, c3v;
#pragma unroll
    for (int r = 0; r < 4; ++r) {
        c2v[r] = b2[4 * lg + r];
        c3v[r] = b3[lm];
    }

    const float* seq = stim + (size_t)bs * T_;
    int b16 = (bs >> 3) * 16;

    // per-lane local-row swizzled bases (SWZ8 invariant under +16-row steps here: 16k keeps bit2)
    int ra2l = lm + 3 * (lg >> 1);
    const unsigned short* pa2 = i1w + ra2l * 16 + (((lg & 1) << 3) ^ SWZ8(ra2l));
    const unsigned short* pb2 = i1w + (ra2l + 6) * 16 + (((lg & 1) << 3) ^ SWZ8(ra2l + 6));
    unsigned short* pw2 = i2w + lm * 16 + ((((lg >> 1) << 3) ^ SWZ8(lm)) + (lg & 1) * 4);
    int ra3l = lm + 9 * (lg >> 1);
    const unsigned short* pa3 = i2w + ra3l * 16 + (((lg & 1) << 3) ^ SWZ8(ra3l));
    const unsigned short* pb3 = i2w + (ra3l + 18) * 16 + (((lg & 1) << 3) ^ SWZ8(ra3l + 18));
    unsigned short* ps3 = s3w + lm * 136 + 4 * lg;
    const unsigned short* pd  = s3w + lm * 136 + lg * 8;
    const unsigned short* xrow = x3b + (size_t)(b16 + lm) * T3P;

    f32x4 dacc;
#pragma unroll
    for (int r = 0; r < 4; ++r) dacc[r] = 0.f;
    float nstc = 0.f;

    // ---- prologue: load + write sinb buf0 for chunk 0 ----
    {
        int c0 = (G * 4) * 512;
        int n_in = min(512, T3_ - c0) + 26;
        sinb[tid] = seq[c0 + tid];
        sinb[tid + 256] = seq[c0 + tid + 256];
        if (tid + 512 < n_in) sinb[tid + 512] = seq[c0 + tid + 512];
    }

    for (int cc = 0; cc < 4; ++cc) {
        int c0 = (G * 4 + cc) * 512;
        int Lv  = min(512, T3_ - c0);
        int n1  = Lv + 24;
        int n1w = min(max(n1 - w0, 0), 176);
        int Lvw = min(max(Lv - w0, 0), 128);
        const float* sb = sinb + (cc & 1) * 544;

        __syncthreads();   // sinb[cc&1] ready (written prev iter / prologue)

        // ---- issue global loads: bq (this chunk) + next-chunk sinb regs ----
        uint4 bq[4];
#pragma unroll
        for (int kk = 0; kk < 4; ++kk) {
            int tg = c0 + w0 + kk * 32 + lg * 8;
            int tc = (tg > 8160) ? 0 : tg;
            bq[kk] = *(const uint4*)(xrow + tc);
        }
        float r0 = 0.f, r1 = 0.f, r2 = 0.f;
        if (cc < 3) {
            int c0n = c0 + 512;
            int n_in_n = min(512, T3_ - c0n) + 26;
            r0 = seq[c0n + tid];
            r1 = seq[c0n + tid + 256];
            r2 = (tid + 512 < n_in_n) ? seq[c0n + tid + 512] : 0.f;
        }

        // ---- conv1 (scalar fp32): wave-private rows [0,176), compute-or-zero ----
#pragma unroll
        for (int k = 0; k < 3; ++k) {
            int r = lane + 64 * k;
            if (r < 176) {
                bool val = r < n1w;
                float s0 = 0.f, s1 = 0.f, s2 = 0.f;
                if (val) {
                    const float* sp = sb + w0 + r;
                    s0 = sp[0]; s1 = sp[1]; s2 = sp[2];
                }
                float a[16];
#pragma unroll
                for (int co = 0; co < 16; ++co)
                    a[co] = val ? fmaxf(b1[co] + s0 * w1[co * 3] + s1 * w1[co * 3 + 1] + s2 * w1[co * 3 + 2], 0.f) : 0.f;
                uint4 p0 = { pk2(a[0], a[1]),   pk2(a[2], a[3]),
                             pk2(a[4], a[5]),   pk2(a[6], a[7]) };
                uint4 p1 = { pk2(a[8], a[9]),   pk2(a[10], a[11]),
                             pk2(a[12], a[13]), pk2(a[14], a[15]) };
                int sw = SWZ8(r);
                *(uint4*)(i1w + r * 16 + sw)       = p0;
                *(uint4*)(i1w + r * 16 + (8 - sw)) = p1;
            }
        }

        // ---- conv2 d=3: i2w rows [0,160), wave-private (no barrier) ----
#pragma unroll
        for (int k = 0; k < 10; ++k) {
            bf16x8 Ba = *(const bf16x8*)(pa2 + 256 * k);
            bf16x8 Bb = *(const bf16x8*)(pb2 + 256 * k);
            f32x4 acc = c2v;
            acc = __builtin_amdgcn_mfma_f32_16x16x32_bf16(W2a, Ba, acc, 0, 0, 0);
            acc = __builtin_amdgcn_mfma_f32_16x16x32_bf16(W2b, Bb, acc, 0, 0, 0);
            uint2 pq = { pk2(fmaxf(acc[0], 0.f), fmaxf(acc[1], 0.f)),
                         pk2(fmaxf(acc[2], 0.f), fmaxf(acc[3], 0.f)) };
            *(uint2*)(pw2 + 256 * k) = pq;
        }

        // ---- conv3 d=9 transposed -> s3w (aliases own i1w; i1 dead after conv2) ----
#pragma unroll
        for (int k = 0; k < 8; ++k) {
            bf16x8 Aa = *(const bf16x8*)(pa3 + 256 * k);
            bf16x8 Ab = *(const bf16x8*)(pb3 + 256 * k);
            f32x4 acc = c3v;
            acc = __builtin_amdgcn_mfma_f32_16x16x32_bf16(Aa, W3a, acc, 0, 0, 0);
            acc = __builtin_amdgcn_mfma_f32_16x16x32_bf16(Ab, W3b, acc, 0, 0, 0);
            int u4 = 16 * k + 4 * lg;
            float v[4];
#pragma unroll
            for (int r = 0; r < 4; ++r) {
                float x = ((u4 + r) < Lvw) ? fmaxf(acc[r], 0.f) : 0.f;
                v[r] = x;
                nstc += x * x;
            }
            uint2 pq = { pk2(v[0], v[1]), pk2(v[2], v[3]) };
            *(uint2*)(ps3 + 16 * k) = pq;
        }

        // ---- dot: own 128-t band (reads own s3w, no barrier) ----
#pragma unroll
        for (int kk = 0; kk < 4; ++kk) {
            bf16x8 Af = *(const bf16x8*)(pd + 32 * kk);
            dacc = __builtin_amdgcn_mfma_f32_16x16x32_bf16(Af, as_bf(bq[kk]), dacc, 0, 0, 0);
        }

        // ---- write next-chunk sinb (other buffer; safe vs conv1 readers of cur) ----
        if (cc < 3) {
            float* sbn = sinb + ((cc + 1) & 1) * 544;
            int n_in_n = min(512, T3_ - (c0 + 512)) + 26;
            sbn[tid] = r0;
            sbn[tid + 256] = r1;
            if (tid + 512 < n_in_n) sbn[tid + 512] = r2;
        }
    }
    __syncthreads();   // all waves done (sinb/i1w reads complete) before red aliases smem head

    // ---- cross-wave reduction in LDS ----
    nstc += __shfl_xor(nstc, 16);
    nstc += __shfl_xor(nstc, 32);
    float* red  = (float*)smem;            // 768 f32 = 3072B
    float* redn = (float*)(smem + 3072);   // 48 f32
    if (wv > 0) {
        *(f32x4*)(red + ((wv - 1) * 64 + lane) * 4) = dacc;
        if (lg == 0) redn[(wv - 1) * 16 + lm] = nstc;
    }
    __syncthreads();
    if (wv == 0) {
#pragma unroll
        for (int w = 0; w < 3; ++w) {
            f32x4 o = *(const f32x4*)(red + (w * 64 + lane) * 4);
#pragma unroll
            for (int r = 0; r < 4; ++r) dacc[r] += o[r];
        }
        int ob = bs * 4 + G;
        *(f32x4*)(dotp + (size_t)ob * 256 + lane * 4) = dacc;
        if (lg == 0)
            nstp[(size_t)ob * 16 + lm] = nstc + redn[lm] + redn[16 + lm] + redn[32 + lm];
    }
}

// =========== K5: reduce partials, cosine, linear head ===========
__global__ __launch_bounds__(256) void k_head(const float* __restrict__ dotp,
                                              const float* __restrict__ nstp,
                                              const float* __restrict__ nxp,
                                              const float* __restrict__ wlin,
                                              const float* __restrict__ blin,
                                              float* __restrict__ out) {
    int bs = blockIdx.x, tid = threadIdx.x;
    int b = bs >> 3;
    __shared__ float nxv[16];
    if (tid < 16) {
        float s = 0.f;
#pragma unroll
        for (int ch = 0; ch < 32; ++ch) s += nxp[((size_t)b * 16 + tid) * 32 + ch];
        nxv[tid] = fmaxf(sqrtf(s), EPS_);
    }
    __syncthreads();
    int i = 4 * (tid >> 6) + (tid & 3);
    int j = (tid >> 2) & 15;
    float dot = 0.f, ss = 0.f;
#pragma unroll
    for (int gw = 0; gw < 4; ++gw) {
        dot += dotp[(size_t)(bs * 4 + gw) * 256 + tid];
        ss  += nstp[(size_t)(bs * 4 + gw) * 16 + i];
    }
    float nstv = fmaxf(sqrtf(ss), EPS_);
    float val = dot / (nstv * nxv[j]) * wlin[i * 16 + j];
#pragma unroll
    for (int m = 32; m > 0; m >>= 1) val += __shfl_down(val, m, 64);
    __shared__ float rd[4];
    if ((tid & 63) == 0) rd[tid >> 6] = val;
    __syncthreads();
    if (tid == 0) out[bs] = rd[0] + rd[1] + rd[2] + rd[3] + blin[0];
}

extern "C" void kernel_launch(void* const* d_in, const int* in_sizes, int n_in,
                              void* d_out, int out_size, void* d_ws, size_t ws_size,
                              hipStream_t stream) {
    const float* eeg   = (const float*)d_in[0];
    const float* stim  = (const float*)d_in[1];
    const float* w_eeg = (const float*)d_in[2];
    const float* b_eeg = (const float*)d_in[3];
    const float* w_e1  = (const float*)d_in[4];
    const float* b_e1  = (const float*)d_in[5];
    const float* w_e2  = (const float*)d_in[6];
    const float* b_e2  = (const float*)d_in[7];
    const float* w_e3  = (const float*)d_in[8];
    const float* b_e3  = (const float*)d_in[9];
    const float* w_s1  = (const float*)d_in[10];
    const float* b_s1  = (const float*)d_in[11];
    const float* w_s2  = (const float*)d_in[12];
    const float* b_s2  = (const float*)d_in[13];
    const float* w_s3  = (const float*)d_in[14];
    const float* b_s3  = (const float*)d_in[15];
    const float* w_lin = (const float*)d_in[16];
    const float* b_lin = (const float*)d_in[17];

    unsigned char* ws = (unsigned char*)d_ws;
    unsigned short* x3b  = (unsigned short*)ws;                 // 16,728,064 B
    float*          nxp  = (float*)(ws + 16728064);             // 131,072 B
    float*          dotp = (float*)(ws + 16859136);             // 2,097,152 B
    float*          nstp = (float*)(ws + 25247744);             // 131,072 B
    unsigned short* x0b  = (unsigned short*)(ws + 25772032);    // 8,388,608 B
    unsigned short* wfE  = (unsigned short*)(ws + 34160640);    // 5,120 B
    unsigned short* wfS  = (unsigned short*)(ws + 34165760);    // 4,096 B
    float*          out  = (float*)d_out;

    k_eeg1x1<<<(B_ * T_) / 256, 256, 0, stream>>>(eeg, w_eeg, b_eeg, x0b,
                                                  w_e1, w_e2, w_e3, w_s2, w_s3, wfE, wfS);
    k_estack<<<dim3(32, B_), 256, 0, stream>>>(x0b, b_e1, b_e2, b_e3, wfE, x3b, nxp);
    k_stim<<<dim3(B_ * S_, 4), 256, 0, stream>>>(stim, w_s1, b_s1, b_s2, b_s3,
                                                 wfS, x3b, dotp, nstp);
    k_head<<<B_ * S_, 256, 0, stream>>>(dotp, nstp, nxp, w_lin, b_lin, out);
}

// Round 12
// 123.088 us; speedup vs baseline: 1.1375x; 1.1375x over previous
//
#include <hip/hip_runtime.h>
#include <hip/hip_bf16.h>
#include <math.h>

#define B_   64
#define S_   8
#define T_   8192
#define T3_  8166      // 8192 - 26
#define T3P  8168      // padded row stride
#define EPS_ 1e-8f
#define SWZ8(r) ((((r) >> 2) & 1) << 3)   // half-swizzle: XOR of the 16B-half by row bit 2

typedef __bf16 bf16x8 __attribute__((ext_vector_type(8)));
typedef float  f32x4  __attribute__((ext_vector_type(4)));
typedef float  f32x2  __attribute__((ext_vector_type(2)));

__device__ __forceinline__ unsigned short f2bf(float x) {
    __hip_bfloat16 h = __float2bfloat16(x);
    return *reinterpret_cast<unsigned short*>(&h);
}
__device__ __forceinline__ unsigned int pk2(float a, float b) {
    return (unsigned int)f2bf(a) | ((unsigned int)f2bf(b) << 16);
}
__device__ __forceinline__ bf16x8 as_bf(uint4 u) { return *reinterpret_cast<bf16x8*>(&u); }

// =========== KA: streaming 1x1 conv 64->8 + (block 0) weight-fragment pack ===========
__global__ __launch_bounds__(256) void k_eeg1x1(const float* __restrict__ eeg,
                                                const float* __restrict__ w,
                                                const float* __restrict__ bias,
                                                unsigned short* __restrict__ x0b,
        const float* __restrict__ w_e1, const float* __restrict__ w_e2, const float* __restrict__ w_e3,
        const float* __restrict__ w_s2, const float* __restrict__ w_s3,
        unsigned short* __restrict__ wfE, unsigned short* __restrict__ wfS) {
    __shared__ float ws[512];
    __shared__ float bs[8];
    int tid = threadIdx.x;

    if (blockIdx.x == 0) {   // ---- pack MFMA weight fragments (bf16) ----
        for (int idx = tid; idx < 2560; idx += 256) {
            int arr = idx >> 9, e = idx & 511;
            int m = e >> 5, k5 = e & 31;
            float v = 0.f;
            if (arr == 0)      { int tap = k5 >> 3, ci = k5 & 7; if (tap < 3) v = w_e1[(m * 8 + ci) * 3 + tap]; }
            else if (arr == 1) { int tap = k5 >> 4, ci = k5 & 15; v = w_e2[(m * 16 + ci) * 3 + tap]; }
            else if (arr == 2) { if (k5 < 16) v = w_e2[(m * 16 + k5) * 3 + 2]; }
            else if (arr == 3) { int tap = k5 >> 4, ci = k5 & 15; v = w_e3[(m * 16 + ci) * 3 + tap]; }
            else               { if (k5 < 16) v = w_e3[(m * 16 + k5) * 3 + 2]; }
            wfE[idx] = f2bf(v);
        }
        for (int idx = tid; idx < 2048; idx += 256) {
            int arr = idx >> 9, e = idx & 511;
            int m = e >> 5, k5 = e & 31;
            int ci = k5 & 15, tap = k5 >> 4;
            float v;
            if (arr == 0)      v = w_s2[(m * 16 + ci) * 3 + tap];
            else if (arr == 1) v = (k5 < 16) ? w_s2[(m * 16 + k5) * 3 + 2] : 0.f;
            else if (arr == 2) v = w_s3[(m * 16 + ci) * 3 + tap];
            else               v = (k5 < 16) ? w_s3[(m * 16 + k5) * 3 + 2] : 0.f;
            wfS[idx] = f2bf(v);
        }
    }

    ws[tid]       = w[tid];
    ws[tid + 256] = w[tid + 256];
    if (tid < 8) bs[tid] = bias[tid];
    __syncthreads();

    int gt = blockIdx.x * 256 + tid;
    const float* ep = eeg + (size_t)gt * 64;

    float acc[8];
#pragma unroll
    for (int c = 0; c < 8; ++c) acc[c] = bs[c];
#pragma unroll
    for (int i = 0; i < 64; i += 4) {
        float4 v = *(const float4*)(ep + i);
#pragma unroll
        for (int c = 0; c < 8; ++c) {
            const float* wp = ws + c * 64 + i;
            acc[c] += v.x * wp[0] + v.y * wp[1] + v.z * wp[2] + v.w * wp[3];
        }
    }
    uint4 p = { pk2(acc[0], acc[1]), pk2(acc[2], acc[3]),
                pk2(acc[4], acc[5]), pk2(acc[6], acc[7]) };
    *(uint4*)(x0b + (size_t)gt * 8) = p;
}

// =========== KB: eeg dilated stack, unrolled const-offset MFMA (R9/R10-verified) ===========
__global__ __launch_bounds__(256) void k_estack(const unsigned short* __restrict__ x0b,
        const float* __restrict__ b1, const float* __restrict__ b2, const float* __restrict__ b3,
        const unsigned short* __restrict__ wfE,
        unsigned short* __restrict__ x3b, float* __restrict__ nxp) {
    __shared__ __align__(16) unsigned char smem[24064];
    unsigned short* x0T = (unsigned short*)smem;
    unsigned short* i1  = (unsigned short*)(smem + 4864);
    unsigned short* i2  = (unsigned short*)(smem + 14592);
    float*          wred= (float*)(smem + 23808);
    unsigned short* st3 = (unsigned short*)smem;

    int tid = threadIdx.x;
    int chunk = blockIdx.x, b = blockIdx.y;
    int wv = tid >> 6, lane = tid & 63, lm = lane & 15, lg = lane >> 4;

    int c0 = chunk * 256;
    int Lv = min(256, T3_ - c0);
    int n_in = Lv + 26, n1 = Lv + 24;

    {
        const unsigned short* src = x0b + ((size_t)b * T_ + c0) * 8;
        uint4 z = {0, 0, 0, 0};
        for (int r = tid; r < 304; r += 256) {
            uint4 v = (r < n_in) ? *(const uint4*)(src + r * 8) : z;
            *(uint4*)(x0T + r * 8) = v;
        }
    }
    for (int idx = tid; idx < (304 - n1) * 8; idx += 256)
        ((unsigned int*)(i1 + n1 * 16))[idx] = 0;
    __syncthreads();

    const bf16x8 W1f = *(const bf16x8*)(wfE +         lm * 32 + 8 * lg);
    const bf16x8 W2a = *(const bf16x8*)(wfE + 512  +  lm * 32 + 8 * lg);
    const bf16x8 W2b = *(const bf16x8*)(wfE + 1024 +  lm * 32 + 8 * lg);
    const bf16x8 W3a = *(const bf16x8*)(wfE + 1536 +  lm * 32 + 8 * lg);
    const bf16x8 W3b = *(const bf16x8*)(wfE + 2048 +  lm * 32 + 8 * lg);
    f32x4 c1v, c2v, c3v;
#pragma unroll
    for (int r = 0; r < 4; ++r) {
        c1v[r] = b1[4 * lg + r];
        c2v[r] = b2[4 * lg + r];
        c3v[r] = b3[lm];
    }

    int t0 = wv * 16 + lm;
    const unsigned short* px0 = x0T + (t0 + lg) * 8;
    unsigned short* pw1 = i1 + t0 * 16 + ((((lg >> 1) << 3) ^ SWZ8(t0)) + (lg & 1) * 4);
    int ra2 = t0 + 3 * (lg >> 1);
    const unsigned short* pa2 = i1 + ra2 * 16 + (((lg & 1) << 3) ^ SWZ8(ra2));
    const unsigned short* pb2 = i1 + (ra2 + 6) * 16 + (((lg & 1) << 3) ^ SWZ8(ra2 + 6));
    unsigned short* pw2 = i2 + t0 * 16 + ((((lg >> 1) << 3) ^ SWZ8(t0)) + (lg & 1) * 4);
    int ra3 = t0 + 9 * (lg >> 1);
    const unsigned short* pa3 = i2 + ra3 * 16 + (((lg & 1) << 3) ^ SWZ8(ra3));
    const unsigned short* pb3 = i2 + (ra3 + 18) * 16 + (((lg & 1) << 3) ^ SWZ8(ra3 + 18));
    unsigned short* ps3 = st3 + lm * 264 + wv * 16 + 4 * lg;

#pragma unroll
    for (int k = 0; k < 5; ++k) {
        if (k == 4 && wv >= 2) break;
        bf16x8 Ba = *(const bf16x8*)(px0 + 512 * k);
        f32x4 acc = __builtin_amdgcn_mfma_f32_16x16x32_bf16(W1f, Ba, c1v, 0, 0, 0);
        if (t0 + 64 * k < n1) {
            uint2 pq = { pk2(fmaxf(acc[0], 0.f), fmaxf(acc[1], 0.f)),
                         pk2(fmaxf(acc[2], 0.f), fmaxf(acc[3], 0.f)) };
            *(uint2*)(pw1 + 1024 * k) = pq;
        }
    }
    __syncthreads();

#pragma unroll
    for (int k = 0; k < 5; ++k) {
        if (k == 4 && wv >= 2) break;
        bf16x8 Ba = *(const bf16x8*)(pa2 + 1024 * k);
        bf16x8 Bb = *(const bf16x8*)(pb2 + 1024 * k);
        f32x4 acc = c2v;
        acc = __builtin_amdgcn_mfma_f32_16x16x32_bf16(W2a, Ba, acc, 0, 0, 0);
        acc = __builtin_amdgcn_mfma_f32_16x16x32_bf16(W2b, Bb, acc, 0, 0, 0);
        uint2 pq = { pk2(fmaxf(acc[0], 0.f), fmaxf(acc[1], 0.f)),
                     pk2(fmaxf(acc[2], 0.f), fmaxf(acc[3], 0.f)) };
        *(uint2*)(pw2 + 1024 * k) = pq;
    }
    __syncthreads();

    float nstc = 0.f;
#pragma unroll
    for (int k = 0; k < 4; ++k) {
        bf16x8 Aa = *(const bf16x8*)(pa3 + 1024 * k);
        bf16x8 Ab = *(const bf16x8*)(pb3 + 1024 * k);
        f32x4 acc = c3v;
        acc = __builtin_amdgcn_mfma_f32_16x16x32_bf16(Aa, W3a, acc, 0, 0, 0);
        acc = __builtin_amdgcn_mfma_f32_16x16x32_bf16(Ab, W3b, acc, 0, 0, 0);
        int u4 = wv * 16 + 4 * lg + 64 * k;
        float v[4];
#pragma unroll
        for (int r = 0; r < 4; ++r) {
            float x = ((u4 + r) < Lv) ? fmaxf(acc[r], 0.f) : 0.f;
            v[r] = x;
            nstc += x * x;
        }
        uint2 pq = { pk2(v[0], v[1]), pk2(v[2], v[3]) };
        *(uint2*)(ps3 + 64 * k) = pq;
    }
    nstc += __shfl_xor(nstc, 16);
    nstc += __shfl_xor(nstc, 32);
    if (lg == 0) wred[wv * 16 + lm] = nstc;
    __syncthreads();

    if (tid < 16) {
        float s = wred[tid] + wred[16 + tid] + wred[32 + tid] + wred[48 + tid];
        nxp[((size_t)b * 16 + tid) * 32 + chunk] = s;
    }
    {
        unsigned short* dst = x3b + (size_t)(b * 16) * T3P + c0;
        for (int idx = tid; idx < 16 * 32; idx += 256) {
            int co = idx >> 5, off = (idx & 31) * 8;
            if (off + 8 <= Lv)
                *(uint4*)(dst + (size_t)co * T3P + off) = *(const uint4*)(st3 + co * 264 + off);
            else
                for (int k = off; k < Lv; ++k) dst[(size_t)co * T3P + k] = st3[co * 264 + k];
        }
        if (chunk == 31 && tid < 16)
            *(unsigned int*)(x3b + (size_t)(b * 16 + tid) * T3P + T3_) = 0;
    }
}

// =========== K4: stim stack — scalar conv1 (f32x2-packed), MFMA conv2/3, merged dot ===========
// grid (512 bs, 4 G); 4 barriers/chunk; in-kernel cross-wave partial reduction. (R10 + VALU trims)
__global__ __launch_bounds__(256, 4) void k_stim(const float* __restrict__ stim,
                                              const float* __restrict__ w1,
                                              const float* __restrict__ b1,
                                              const float* __restrict__ b2,
                                              const float* __restrict__ b3,
                                              const unsigned short* __restrict__ wfS,
                                              const unsigned short* __restrict__ x3b,
                                              float* __restrict__ dotp, float* __restrict__ nstp) {
    // LDS: sinb f32[548] @0 (2192) ; i1 u16[560][16] @2192 (17920) ; i2 u16[544][16] @20112 (17408)
    // s3 u16[16][520] aliases i1 ; red f32[816] @0 aliases sinb+i1 head (after final barrier only)
    __shared__ __align__(16) unsigned char smem[37520];
    float*          sinb = (float*)smem;
    unsigned short* i1   = (unsigned short*)(smem + 2192);
    unsigned short* i2   = (unsigned short*)(smem + 20112);
    unsigned short* s3   = i1;

    int tid  = threadIdx.x;
    int bs   = blockIdx.x;
    int G    = blockIdx.y;
    int wv   = tid >> 6;
    int lane = tid & 63;
    int lm   = lane & 15;
    int lg   = lane >> 4;

    const bf16x8 W2a = *(const bf16x8*)(wfS +         lm * 32 + 8 * lg);
    const bf16x8 W2b = *(const bf16x8*)(wfS + 512  +  lm * 32 + 8 * lg);
    const bf16x8 W3a = *(const bf16x8*)(wfS + 1024 +  lm * 32 + 8 * lg);
    const bf16x8 W3b = *(const bf16x8*)(wfS + 1536 +  lm * 32 + 8 * lg);
    f32x4 c2v, c3v;
#pragma unroll
    for (int r = 0; r < 4; ++r) {
        c2v[r] = b2[4 * lg + r];
        c3v[r] = b3[lm];          // transposed conv3: C col = channel = lm
    }

    const float* seq = stim + (size_t)bs * T_;
    int b16 = (bs >> 3) * 16;

    // ---- hoisted per-lane swizzled bases (SWZ8 invariant under +64-row steps) ----
    int t0   = wv * 16 + lm;
    int ra2 = t0 + 3 * (lg >> 1);
    const unsigned short* pa2 = i1 + ra2 * 16 + (((lg & 1) << 3) ^ SWZ8(ra2));
    const unsigned short* pb2 = i1 + (ra2 + 6) * 16 + (((lg & 1) << 3) ^ SWZ8(ra2 + 6));
    unsigned short* pw2 = i2 + t0 * 16 + ((((lg >> 1) << 3) ^ SWZ8(t0)) + (lg & 1) * 4);
    int ra3 = t0 + 9 * (lg >> 1);
    const unsigned short* pa3 = i2 + ra3 * 16 + (((lg & 1) << 3) ^ SWZ8(ra3));
    const unsigned short* pb3 = i2 + (ra3 + 18) * 16 + (((lg & 1) << 3) ^ SWZ8(ra3 + 18));
    unsigned short* ps3 = s3 + lm * 520 + wv * 16 + 4 * lg;
    const unsigned short* pd  = s3 + lm * 520 + wv * 128 + lg * 8;
    const unsigned short* xrow = x3b + (size_t)(b16 + lm) * T3P;

    f32x4 dacc;
#pragma unroll
    for (int r = 0; r < 4; ++r) dacc[r] = 0.f;
    float nstc = 0.f;
    uint4 bq[4];

    // ---- preload chunk 0 sinb into regs ----
    int c0 = (G * 4) * 512;
    int n_in = min(512, T3_ - c0) + 26;
    float r0 = seq[c0 + tid];
    float r1 = seq[c0 + tid + 256];
    float r2 = (tid + 512 < n_in) ? seq[c0 + tid + 512] : 0.f;

    for (int cc = 0; cc < 4; ++cc) {
        c0 = (G * 4 + cc) * 512;
        int Lv = min(512, T3_ - c0);
        int n1 = Lv + 24;           // always even (536 or 510)
        n_in = Lv + 26;

        // ---- phase X: dot(prev chunk) from s3 + bq(prev); write sinb(cc) ----
        if (cc > 0) {
#pragma unroll
            for (int kk = 0; kk < 4; ++kk) {
                bf16x8 Af = *(const bf16x8*)(pd + 32 * kk);
                dacc = __builtin_amdgcn_mfma_f32_16x16x32_bf16(Af, as_bf(bq[kk]), dacc, 0, 0, 0);
            }
        }
        sinb[tid] = r0;
        sinb[tid + 256] = r1;
        if (tid + 512 < n_in) sinb[tid + 512] = r2;
        __syncthreads();

        // ---- conv1 phase: issue bq(cc) + next-sinb global loads; zero i1 tail; packed conv1 ----
        if (c0 < 7680) {            // fast path: no clamp needed (max tg = c0+504 <= 8160)
#pragma unroll
            for (int kk = 0; kk < 4; ++kk)
                bq[kk] = *(const uint4*)(xrow + c0 + wv * 128 + kk * 32 + lg * 8);
        } else {
#pragma unroll
            for (int kk = 0; kk < 4; ++kk) {
                int tg = c0 + wv * 128 + kk * 32 + lg * 8;
                int tc = (tg > 8160) ? 0 : tg;
                bq[kk] = *(const uint4*)(xrow + tc);
            }
        }
        if (cc < 3) {
            int c0n = c0 + 512;
            int n_in_n = min(512, T3_ - c0n) + 26;
            r0 = seq[c0n + tid];
            r1 = seq[c0n + tid + 256];
            r2 = (tid + 512 < n_in_n) ? seq[c0n + tid + 512] : 0.f;
        }
        for (int z = tid; z < (560 - n1) * 8; z += 256)
            ((unsigned int*)(i1 + n1 * 16))[z] = 0;

        {   // rows rA=tid (<256<n1 always), rB=tid+256 (guarded), rC=tid+512 (guarded)
            int rA = tid, rB = tid + 256;
            bool vB = rB < n1;
            float sa0 = sinb[rA], sa1 = sinb[rA + 1], sa2 = sinb[rA + 2];
            float sb0 = vB ? sinb[rB] : 0.f, sb1 = vB ? sinb[rB + 1] : 0.f, sb2 = vB ? sinb[rB + 2] : 0.f;
            f32x2 s0 = { sa0, sb0 }, s1 = { sa1, sb1 }, s2 = { sa2, sb2 };
            f32x2 a[16];
#pragma unroll
            for (int co = 0; co < 16; ++co) {
                f32x2 t = (f32x2)(b1[co]) + s0 * (f32x2)(w1[co * 3])
                        + s1 * (f32x2)(w1[co * 3 + 1]) + s2 * (f32x2)(w1[co * 3 + 2]);
                a[co].x = fmaxf(t.x, 0.f);
                a[co].y = fmaxf(t.y, 0.f);
            }
            int sw = SWZ8(rA);      // SWZ8(rB) == SWZ8(rA): +256 keeps bit 2
            uint4 p0 = { pk2(a[0].x, a[1].x),   pk2(a[2].x, a[3].x),
                         pk2(a[4].x, a[5].x),   pk2(a[6].x, a[7].x) };
            uint4 p1 = { pk2(a[8].x, a[9].x),   pk2(a[10].x, a[11].x),
                         pk2(a[12].x, a[13].x), pk2(a[14].x, a[15].x) };
            *(uint4*)(i1 + rA * 16 + sw)       = p0;
            *(uint4*)(i1 + rA * 16 + (8 - sw)) = p1;
            if (vB) {
                uint4 q0 = { pk2(a[0].y, a[1].y),   pk2(a[2].y, a[3].y),
                             pk2(a[4].y, a[5].y),   pk2(a[6].y, a[7].y) };
                uint4 q1 = { pk2(a[8].y, a[9].y),   pk2(a[10].y, a[11].y),
                             pk2(a[12].y, a[13].y), pk2(a[14].y, a[15].y) };
                *(uint4*)(i1 + rB * 16 + sw)       = q0;
                *(uint4*)(i1 + rB * 16 + (8 - sw)) = q1;
            }
            int rC = tid + 512;
            if (rC < n1) {          // full chunks only: 24 rows
                float c0s = sinb[rC], c1s = sinb[rC + 1], c2s = sinb[rC + 2];
                float av[16];
#pragma unroll
                for (int co = 0; co < 16; ++co)
                    av[co] = fmaxf(b1[co] + c0s * w1[co * 3] + c1s * w1[co * 3 + 1] + c2s * w1[co * 3 + 2], 0.f);
                int swc = SWZ8(rC);
                uint4 u0 = { pk2(av[0], av[1]),   pk2(av[2], av[3]),
                             pk2(av[4], av[5]),   pk2(av[6], av[7]) };
                uint4 u1 = { pk2(av[8], av[9]),   pk2(av[10], av[11]),
                             pk2(av[12], av[13]), pk2(av[14], av[15]) };
                *(uint4*)(i1 + rC * 16 + swc)       = u0;
                *(uint4*)(i1 + rC * 16 + (8 - swc)) = u1;
            }
        }
        __syncthreads();

        // ---- conv2 d=3 ----
#pragma unroll
        for (int k = 0; k < 9; ++k) {
            if (k == 8 && wv >= 2) break;
            bf16x8 Ba = *(const bf16x8*)(pa2 + 1024 * k);
            bf16x8 Bb = *(const bf16x8*)(pb2 + 1024 * k);
            f32x4 acc = c2v;
            acc = __builtin_amdgcn_mfma_f32_16x16x32_bf16(W2a, Ba, acc, 0, 0, 0);
            acc = __builtin_amdgcn_mfma_f32_16x16x32_bf16(W2b, Bb, acc, 0, 0, 0);
            uint2 pq = { pk2(fmaxf(acc[0], 0.f), fmaxf(acc[1], 0.f)),
                         pk2(fmaxf(acc[2], 0.f), fmaxf(acc[3], 0.f)) };
            *(uint2*)(pw2 + 1024 * k) = pq;
        }
        __syncthreads();

        // ---- conv3 d=9 transposed -> s3 + norm (uniform fast path when Lv==512) ----
        if (Lv == 512) {
#pragma unroll
            for (int k = 0; k < 8; ++k) {
                bf16x8 Aa = *(const bf16x8*)(pa3 + 1024 * k);
                bf16x8 Ab = *(const bf16x8*)(pb3 + 1024 * k);
                f32x4 acc = c3v;
                acc = __builtin_amdgcn_mfma_f32_16x16x32_bf16(Aa, W3a, acc, 0, 0, 0);
                acc = __builtin_amdgcn_mfma_f32_16x16x32_bf16(Ab, W3b, acc, 0, 0, 0);
                float v0 = fmaxf(acc[0], 0.f), v1 = fmaxf(acc[1], 0.f);
                float v2 = fmaxf(acc[2], 0.f), v3 = fmaxf(acc[3], 0.f);
                nstc += v0 * v0 + v1 * v1 + v2 * v2 + v3 * v3;
                uint2 pq = { pk2(v0, v1), pk2(v2, v3) };
                *(uint2*)(ps3 + 64 * k) = pq;
            }
        } else {
#pragma unroll
            for (int k = 0; k < 8; ++k) {
                bf16x8 Aa = *(const bf16x8*)(pa3 + 1024 * k);
                bf16x8 Ab = *(const bf16x8*)(pb3 + 1024 * k);
                f32x4 acc = c3v;
                acc = __builtin_amdgcn_mfma_f32_16x16x32_bf16(Aa, W3a, acc, 0, 0, 0);
                acc = __builtin_amdgcn_mfma_f32_16x16x32_bf16(Ab, W3b, acc, 0, 0, 0);
                int u4 = wv * 16 + 4 * lg + 64 * k;
                float v[4];
#pragma unroll
                for (int r = 0; r < 4; ++r) {
                    float x = ((u4 + r) < Lv) ? fmaxf(acc[r], 0.f) : 0.f;
                    v[r] = x;
                    nstc += x * x;
                }
                uint2 pq = { pk2(v[0], v[1]), pk2(v[2], v[3]) };
                *(uint2*)(ps3 + 64 * k) = pq;
            }
        }
        __syncthreads();
    }

    // ---- final dot (chunk 3) ----
#pragma unroll
    for (int kk = 0; kk < 4; ++kk) {
        bf16x8 Af = *(const bf16x8*)(pd + 32 * kk);
        dacc = __builtin_amdgcn_mfma_f32_16x16x32_bf16(Af, as_bf(bq[kk]), dacc, 0, 0, 0);
    }
    __syncthreads();   // all dot reads of s3 done before red (aliases smem head) is written

    // ---- cross-wave reduction in LDS ----
    nstc += __shfl_xor(nstc, 16);
    nstc += __shfl_xor(nstc, 32);
    float* red  = (float*)smem;            // 768 f32 = 3072B
    float* redn = (float*)(smem + 3072);   // 48 f32
    if (wv > 0) {
        *(f32x4*)(red + ((wv - 1) * 64 + lane) * 4) = dacc;
        if (lg == 0) redn[(wv - 1) * 16 + lm] = nstc;
    }
    __syncthreads();
    if (wv == 0) {
#pragma unroll
        for (int w = 0; w < 3; ++w) {
            f32x4 o = *(const f32x4*)(red + (w * 64 + lane) * 4);
#pragma unroll
            for (int r = 0; r < 4; ++r) dacc[r] += o[r];
        }
        int ob = bs * 4 + G;
        *(f32x4*)(dotp + (size_t)ob * 256 + lane * 4) = dacc;
        if (lg == 0)
            nstp[(size_t)ob * 16 + lm] = nstc + redn[lm] + redn[16 + lm] + redn[32 + lm];
    }
}

// =========== K5: reduce partials, cosine, linear head ===========
__global__ __launch_bounds__(256) void k_head(const float* __restrict__ dotp,
                                              const float* __restrict__ nstp,
                                              const float* __restrict__ nxp,
                                              const float* __restrict__ wlin,
                                              const float* __restrict__ blin,
                                              float* __restrict__ out) {
    int bs = blockIdx.x, tid = threadIdx.x;
    int b = bs >> 3;
    __shared__ float nxv[16];
    if (tid < 16) {
        float s = 0.f;
#pragma unroll
        for (int ch = 0; ch < 32; ++ch) s += nxp[((size_t)b * 16 + tid) * 32 + ch];
        nxv[tid] = fmaxf(sqrtf(s), EPS_);
    }
    __syncthreads();
    int i = 4 * (tid >> 6) + (tid & 3);
    int j = (tid >> 2) & 15;
    float dot = 0.f, ss = 0.f;
#pragma unroll
    for (int gw = 0; gw < 4; ++gw) {
        dot += dotp[(size_t)(bs * 4 + gw) * 256 + tid];
        ss  += nstp[(size_t)(bs * 4 + gw) * 16 + i];
    }
    float nstv = fmaxf(sqrtf(ss), EPS_);
    float val = dot / (nstv * nxv[j]) * wlin[i * 16 + j];
#pragma unroll
    for (int m = 32; m > 0; m >>= 1) val += __shfl_down(val, m, 64);
    __shared__ float rd[4];
    if ((tid & 63) == 0) rd[tid >> 6] = val;
    __syncthreads();
    if (tid == 0) out[bs] = rd[0] + rd[1] + rd[2] + rd[3] + blin[0];
}

extern "C" void kernel_launch(void* const* d_in, const int* in_sizes, int n_in,
                              void* d_out, int out_size, void* d_ws, size_t ws_size,
                              hipStream_t stream) {
    const float* eeg   = (const float*)d_in[0];
    const float* stim  = (const float*)d_in[1];
    const float* w_eeg = (const float*)d_in[2];
    const float* b_eeg = (const float*)d_in[3];
    const float* w_e1  = (const float*)d_in[4];
    const float* b_e1  = (const float*)d_in[5];
    const float* w_e2  = (const float*)d_in[6];
    const float* b_e2  = (const float*)d_in[7];
    const float* w_e3  = (const float*)d_in[8];
    const float* b_e3  = (const float*)d_in[9];
    const float* w_s1  = (const float*)d_in[10];
    const float* b_s1  = (const float*)d_in[11];
    const float* w_s2  = (const float*)d_in[12];
    const float* b_s2  = (const float*)d_in[13];
    const float* w_s3  = (const float*)d_in[14];
    const float* b_s3  = (const float*)d_in[15];
    const float* w_lin = (const float*)d_in[16];
    const float* b_lin = (const float*)d_in[17];

    unsigned char* ws = (unsigned char*)d_ws;
    unsigned short* x3b  = (unsigned short*)ws;                 // 16,728,064 B
    float*          nxp  = (float*)(ws + 16728064);             // 131,072 B
    float*          dotp = (float*)(ws + 16859136);             // 2,097,152 B
    float*          nstp = (float*)(ws + 25247744);             // 131,072 B
    unsigned short* x0b  = (unsigned short*)(ws + 25772032);    // 8,388,608 B
    unsigned short* wfE  = (unsigned short*)(ws + 34160640);    // 5,120 B
    unsigned short* wfS  = (unsigned short*)(ws + 34165760);    // 4,096 B
    float*          out  = (float*)d_out;

    k_eeg1x1<<<(B_ * T_) / 256, 256, 0, stream>>>(eeg, w_eeg, b_eeg, x0b,
                                                  w_e1, w_e2, w_e3, w_s2, w_s3, wfE, wfS);
    k_estack<<<dim3(32, B_), 256, 0, stream>>>(x0b, b_e1, b_e2, b_e3, wfE, x3b, nxp);
    k_stim<<<dim3(B_ * S_, 4), 256, 0, stream>>>(stim, w_s1, b_s1, b_s2, b_s3,
                                                 wfS, x3b, dotp, nstp);
    k_head<<<B_ * S_, 256, 0, stream>>>(dotp, nstp, nxp, w_lin, b_lin, out);
}

// Round 13
// 113.803 us; speedup vs baseline: 1.2303x; 1.0816x over previous
//
#include <hip/hip_runtime.h>
#include <hip/hip_bf16.h>
#include <math.h>

#define B_   64
#define S_   8
#define T_   8192
#define T3_  8166      // 8192 - 26
#define T3P  8168      // padded row stride
#define EPS_ 1e-8f
#define SWZ8(r) ((((r) >> 2) & 1) << 3)   // half-swizzle: XOR of the 16B-half by row bit 2

typedef __bf16 bf16x8 __attribute__((ext_vector_type(8)));
typedef float  f32x4  __attribute__((ext_vector_type(4)));

__device__ __forceinline__ unsigned short f2bf(float x) {
    __hip_bfloat16 h = __float2bfloat16(x);
    return *reinterpret_cast<unsigned short*>(&h);
}
__device__ __forceinline__ unsigned int pk2(float a, float b) {
    return (unsigned int)f2bf(a) | ((unsigned int)f2bf(b) << 16);
}
__device__ __forceinline__ bf16x8 as_bf(uint4 u) { return *reinterpret_cast<bf16x8*>(&u); }

// =========== KA: streaming 1x1 conv 64->8 + (block 0) weight-fragment pack ===========
__global__ __launch_bounds__(256) void k_eeg1x1(const float* __restrict__ eeg,
                                                const float* __restrict__ w,
                                                const float* __restrict__ bias,
                                                unsigned short* __restrict__ x0b,
        const float* __restrict__ w_e1, const float* __restrict__ w_e2, const float* __restrict__ w_e3,
        const float* __restrict__ w_s2, const float* __restrict__ w_s3,
        unsigned short* __restrict__ wfE, unsigned short* __restrict__ wfS) {
    __shared__ float ws[512];
    __shared__ float bs[8];
    int tid = threadIdx.x;

    if (blockIdx.x == 0) {   // ---- pack MFMA weight fragments (bf16) ----
        for (int idx = tid; idx < 2560; idx += 256) {
            int arr = idx >> 9, e = idx & 511;
            int m = e >> 5, k5 = e & 31;
            float v = 0.f;
            if (arr == 0)      { int tap = k5 >> 3, ci = k5 & 7; if (tap < 3) v = w_e1[(m * 8 + ci) * 3 + tap]; }
            else if (arr == 1) { int tap = k5 >> 4, ci = k5 & 15; v = w_e2[(m * 16 + ci) * 3 + tap]; }
            else if (arr == 2) { if (k5 < 16) v = w_e2[(m * 16 + k5) * 3 + 2]; }
            else if (arr == 3) { int tap = k5 >> 4, ci = k5 & 15; v = w_e3[(m * 16 + ci) * 3 + tap]; }
            else               { if (k5 < 16) v = w_e3[(m * 16 + k5) * 3 + 2]; }
            wfE[idx] = f2bf(v);
        }
        for (int idx = tid; idx < 2048; idx += 256) {
            int arr = idx >> 9, e = idx & 511;
            int m = e >> 5, k5 = e & 31;
            int ci = k5 & 15, tap = k5 >> 4;
            float v;
            if (arr == 0)      v = w_s2[(m * 16 + ci) * 3 + tap];
            else if (arr == 1) v = (k5 < 16) ? w_s2[(m * 16 + k5) * 3 + 2] : 0.f;
            else if (arr == 2) v = w_s3[(m * 16 + ci) * 3 + tap];
            else               v = (k5 < 16) ? w_s3[(m * 16 + k5) * 3 + 2] : 0.f;
            wfS[idx] = f2bf(v);
        }
    }

    ws[tid]       = w[tid];
    ws[tid + 256] = w[tid + 256];
    if (tid < 8) bs[tid] = bias[tid];
    __syncthreads();

    int gt = blockIdx.x * 256 + tid;
    const float* ep = eeg + (size_t)gt * 64;

    float acc[8];
#pragma unroll
    for (int c = 0; c < 8; ++c) acc[c] = bs[c];
#pragma unroll
    for (int i = 0; i < 64; i += 4) {
        float4 v = *(const float4*)(ep + i);
#pragma unroll
        for (int c = 0; c < 8; ++c) {
            const float* wp = ws + c * 64 + i;
            acc[c] += v.x * wp[0] + v.y * wp[1] + v.z * wp[2] + v.w * wp[3];
        }
    }
    uint4 p = { pk2(acc[0], acc[1]), pk2(acc[2], acc[3]),
                pk2(acc[4], acc[5]), pk2(acc[6], acc[7]) };
    *(uint4*)(x0b + (size_t)gt * 8) = p;
}

// =========== KB: eeg dilated stack, unrolled const-offset MFMA (R9-verified) ===========
__global__ __launch_bounds__(256) void k_estack(const unsigned short* __restrict__ x0b,
        const float* __restrict__ b1, const float* __restrict__ b2, const float* __restrict__ b3,
        const unsigned short* __restrict__ wfE,
        unsigned short* __restrict__ x3b, float* __restrict__ nxp) {
    __shared__ __align__(16) unsigned char smem[24064];
    unsigned short* x0T = (unsigned short*)smem;
    unsigned short* i1  = (unsigned short*)(smem + 4864);
    unsigned short* i2  = (unsigned short*)(smem + 14592);
    float*          wred= (float*)(smem + 23808);
    unsigned short* st3 = (unsigned short*)smem;

    int tid = threadIdx.x;
    int chunk = blockIdx.x, b = blockIdx.y;
    int wv = tid >> 6, lane = tid & 63, lm = lane & 15, lg = lane >> 4;

    int c0 = chunk * 256;
    int Lv = min(256, T3_ - c0);
    int n_in = Lv + 26, n1 = Lv + 24;

    {
        const unsigned short* src = x0b + ((size_t)b * T_ + c0) * 8;
        uint4 z = {0, 0, 0, 0};
        for (int r = tid; r < 304; r += 256) {
            uint4 v = (r < n_in) ? *(const uint4*)(src + r * 8) : z;
            *(uint4*)(x0T + r * 8) = v;
        }
    }
    for (int idx = tid; idx < (304 - n1) * 8; idx += 256)
        ((unsigned int*)(i1 + n1 * 16))[idx] = 0;
    __syncthreads();

    const bf16x8 W1f = *(const bf16x8*)(wfE +         lm * 32 + 8 * lg);
    const bf16x8 W2a = *(const bf16x8*)(wfE + 512  +  lm * 32 + 8 * lg);
    const bf16x8 W2b = *(const bf16x8*)(wfE + 1024 +  lm * 32 + 8 * lg);
    const bf16x8 W3a = *(const bf16x8*)(wfE + 1536 +  lm * 32 + 8 * lg);
    const bf16x8 W3b = *(const bf16x8*)(wfE + 2048 +  lm * 32 + 8 * lg);
    f32x4 c1v, c2v, c3v;
#pragma unroll
    for (int r = 0; r < 4; ++r) {
        c1v[r] = b1[4 * lg + r];
        c2v[r] = b2[4 * lg + r];
        c3v[r] = b3[lm];
    }

    int t0 = wv * 16 + lm;
    const unsigned short* px0 = x0T + (t0 + lg) * 8;
    unsigned short* pw1 = i1 + t0 * 16 + ((((lg >> 1) << 3) ^ SWZ8(t0)) + (lg & 1) * 4);
    int ra2 = t0 + 3 * (lg >> 1);
    const unsigned short* pa2 = i1 + ra2 * 16 + (((lg & 1) << 3) ^ SWZ8(ra2));
    const unsigned short* pb2 = i1 + (ra2 + 6) * 16 + (((lg & 1) << 3) ^ SWZ8(ra2 + 6));
    unsigned short* pw2 = i2 + t0 * 16 + ((((lg >> 1) << 3) ^ SWZ8(t0)) + (lg & 1) * 4);
    int ra3 = t0 + 9 * (lg >> 1);
    const unsigned short* pa3 = i2 + ra3 * 16 + (((lg & 1) << 3) ^ SWZ8(ra3));
    const unsigned short* pb3 = i2 + (ra3 + 18) * 16 + (((lg & 1) << 3) ^ SWZ8(ra3 + 18));
    unsigned short* ps3 = st3 + lm * 264 + wv * 16 + 4 * lg;

#pragma unroll
    for (int k = 0; k < 5; ++k) {
        if (k == 4 && wv >= 2) break;
        bf16x8 Ba = *(const bf16x8*)(px0 + 512 * k);
        f32x4 acc = __builtin_amdgcn_mfma_f32_16x16x32_bf16(W1f, Ba, c1v, 0, 0, 0);
        if (t0 + 64 * k < n1) {
            uint2 pq = { pk2(fmaxf(acc[0], 0.f), fmaxf(acc[1], 0.f)),
                         pk2(fmaxf(acc[2], 0.f), fmaxf(acc[3], 0.f)) };
            *(uint2*)(pw1 + 1024 * k) = pq;
        }
    }
    __syncthreads();

#pragma unroll
    for (int k = 0; k < 5; ++k) {
        if (k == 4 && wv >= 2) break;
        bf16x8 Ba = *(const bf16x8*)(pa2 + 1024 * k);
        bf16x8 Bb = *(const bf16x8*)(pb2 + 1024 * k);
        f32x4 acc = c2v;
        acc = __builtin_amdgcn_mfma_f32_16x16x32_bf16(W2a, Ba, acc, 0, 0, 0);
        acc = __builtin_amdgcn_mfma_f32_16x16x32_bf16(W2b, Bb, acc, 0, 0, 0);
        uint2 pq = { pk2(fmaxf(acc[0], 0.f), fmaxf(acc[1], 0.f)),
                     pk2(fmaxf(acc[2], 0.f), fmaxf(acc[3], 0.f)) };
        *(uint2*)(pw2 + 1024 * k) = pq;
    }
    __syncthreads();

    float nstc = 0.f;
#pragma unroll
    for (int k = 0; k < 4; ++k) {
        bf16x8 Aa = *(const bf16x8*)(pa3 + 1024 * k);
        bf16x8 Ab = *(const bf16x8*)(pb3 + 1024 * k);
        f32x4 acc = c3v;
        acc = __builtin_amdgcn_mfma_f32_16x16x32_bf16(Aa, W3a, acc, 0, 0, 0);
        acc = __builtin_amdgcn_mfma_f32_16x16x32_bf16(Ab, W3b, acc, 0, 0, 0);
        int u4 = wv * 16 + 4 * lg + 64 * k;
        float v[4];
#pragma unroll
        for (int r = 0; r < 4; ++r) {
            float x = ((u4 + r) < Lv) ? fmaxf(acc[r], 0.f) : 0.f;
            v[r] = x;
            nstc += x * x;
        }
        uint2 pq = { pk2(v[0], v[1]), pk2(v[2], v[3]) };
        *(uint2*)(ps3 + 64 * k) = pq;
    }
    nstc += __shfl_xor(nstc, 16);
    nstc += __shfl_xor(nstc, 32);
    if (lg == 0) wred[wv * 16 + lm] = nstc;
    __syncthreads();

    if (tid < 16) {
        float s = wred[tid] + wred[16 + tid] + wred[32 + tid] + wred[48 + tid];
        nxp[((size_t)b * 16 + tid) * 32 + chunk] = s;
    }
    {
        unsigned short* dst = x3b + (size_t)(b * 16) * T3P + c0;
        for (int idx = tid; idx < 16 * 32; idx += 256) {
            int co = idx >> 5, off = (idx & 31) * 8;
            if (off + 8 <= Lv)
                *(uint4*)(dst + (size_t)co * T3P + off) = *(const uint4*)(st3 + co * 264 + off);
            else
                for (int k = off; k < Lv; ++k) dst[(size_t)co * T3P + k] = st3[co * 264 + k];
        }
        if (chunk == 31 && tid < 16)
            *(unsigned int*)(x3b + (size_t)(b * 16 + tid) * T3P + T3_) = 0;
    }
}

// =========== K4: stim stack — scalar conv1 (fp32), MFMA conv2/3, merged dot phase ===========
// grid (512 bs, 4 G); 4 barriers/chunk; in-kernel cross-wave partial reduction.
__global__ __launch_bounds__(256, 4) void k_stim(const float* __restrict__ stim,
                                              const float* __restrict__ w1,
                                              const float* __restrict__ b1,
                                              const float* __restrict__ b2,
                                              const float* __restrict__ b3,
                                              const unsigned short* __restrict__ wfS,
                                              const unsigned short* __restrict__ x3b,
                                              float* __restrict__ dotp, float* __restrict__ nstp) {
    // LDS: sinb f32[548] @0 (2192) ; i1 u16[560][16] @2192 (17920) ; i2 u16[544][16] @20112 (17408)
    // s3 u16[16][520] aliases i1 ; red f32[816] @0 aliases sinb+i1 head (after final barrier only)
    __shared__ __align__(16) unsigned char smem[37520];
    float*          sinb = (float*)smem;
    unsigned short* i1   = (unsigned short*)(smem + 2192);
    unsigned short* i2   = (unsigned short*)(smem + 20112);
    unsigned short* s3   = i1;

    int tid  = threadIdx.x;
    int bs   = blockIdx.x;
    int G    = blockIdx.y;
    int wv   = tid >> 6;
    int lane = tid & 63;
    int lm   = lane & 15;
    int lg   = lane >> 4;

    const bf16x8 W2a = *(const bf16x8*)(wfS +         lm * 32 + 8 * lg);
    const bf16x8 W2b = *(const bf16x8*)(wfS + 512  +  lm * 32 + 8 * lg);
    const bf16x8 W3a = *(const bf16x8*)(wfS + 1024 +  lm * 32 + 8 * lg);
    const bf16x8 W3b = *(const bf16x8*)(wfS + 1536 +  lm * 32 + 8 * lg);
    f32x4 c2v, c3v;
#pragma unroll
    for (int r = 0; r < 4; ++r) {
        c2v[r] = b2[4 * lg + r];
        c3v[r] = b3[lm];          // transposed conv3: C col = channel = lm
    }

    const float* seq = stim + (size_t)bs * T_;
    int b16 = (bs >> 3) * 16;

    // ---- hoisted per-lane swizzled bases (SWZ8 invariant under +64-row steps) ----
    int t0   = wv * 16 + lm;
    int ra2 = t0 + 3 * (lg >> 1);
    const unsigned short* pa2 = i1 + ra2 * 16 + (((lg & 1) << 3) ^ SWZ8(ra2));
    const unsigned short* pb2 = i1 + (ra2 + 6) * 16 + (((lg & 1) << 3) ^ SWZ8(ra2 + 6));
    unsigned short* pw2 = i2 + t0 * 16 + ((((lg >> 1) << 3) ^ SWZ8(t0)) + (lg & 1) * 4);
    int ra3 = t0 + 9 * (lg >> 1);
    const unsigned short* pa3 = i2 + ra3 * 16 + (((lg & 1) << 3) ^ SWZ8(ra3));
    const unsigned short* pb3 = i2 + (ra3 + 18) * 16 + (((lg & 1) << 3) ^ SWZ8(ra3 + 18));
    unsigned short* ps3 = s3 + lm * 520 + wv * 16 + 4 * lg;
    const unsigned short* pd  = s3 + lm * 520 + wv * 128 + lg * 8;
    const unsigned short* xrow = x3b + (size_t)(b16 + lm) * T3P;

    f32x4 dacc;
#pragma unroll
    for (int r = 0; r < 4; ++r) dacc[r] = 0.f;
    float nstc = 0.f;
    uint4 bq[4];

    // ---- preload chunk 0 sinb into regs ----
    int c0 = (G * 4) * 512;
    int n_in = min(512, T3_ - c0) + 26;
    float r0 = seq[c0 + tid];
    float r1 = seq[c0 + tid + 256];
    float r2 = (tid + 512 < n_in) ? seq[c0 + tid + 512] : 0.f;

    for (int cc = 0; cc < 4; ++cc) {
        c0 = (G * 4 + cc) * 512;
        int Lv = min(512, T3_ - c0);
        int n1 = Lv + 24;
        n_in = Lv + 26;

        // ---- phase X: dot(prev chunk) from s3 + bq(prev); write sinb(cc) ----
        if (cc > 0) {
#pragma unroll
            for (int kk = 0; kk < 4; ++kk) {
                bf16x8 Af = *(const bf16x8*)(pd + 32 * kk);
                dacc = __builtin_amdgcn_mfma_f32_16x16x32_bf16(Af, as_bf(bq[kk]), dacc, 0, 0, 0);
            }
        }
        sinb[tid] = r0;
        sinb[tid + 256] = r1;
        if (tid + 512 < n_in) sinb[tid + 512] = r2;
        __syncthreads();

        // ---- conv1 phase: issue bq(cc) + next-sinb global loads; zero i1 tail; scalar conv1 ----
#pragma unroll
        for (int kk = 0; kk < 4; ++kk) {
            int tg = c0 + wv * 128 + kk * 32 + lg * 8;
            int tc = (tg > 8160) ? 0 : tg;
            bq[kk] = *(const uint4*)(xrow + tc);
        }
        if (cc < 3) {
            int c0n = c0 + 512;
            int n_in_n = min(512, T3_ - c0n) + 26;
            r0 = seq[c0n + tid];
            r1 = seq[c0n + tid + 256];
            r2 = (tid + 512 < n_in_n) ? seq[c0n + tid + 512] : 0.f;
        }
        for (int z = tid; z < (560 - n1) * 8; z += 256)
            ((unsigned int*)(i1 + n1 * 16))[z] = 0;
#pragma unroll
        for (int k = 0; k < 3; ++k) {
            int v = tid + 256 * k;
            if (v < n1) {
                float s0 = sinb[v], s1 = sinb[v + 1], s2 = sinb[v + 2];
                float a[16];
#pragma unroll
                for (int co = 0; co < 16; ++co)
                    a[co] = fmaxf(b1[co] + s0 * w1[co * 3] + s1 * w1[co * 3 + 1] + s2 * w1[co * 3 + 2], 0.f);
                uint4 p0 = { pk2(a[0], a[1]),   pk2(a[2], a[3]),
                             pk2(a[4], a[5]),   pk2(a[6], a[7]) };
                uint4 p1 = { pk2(a[8], a[9]),   pk2(a[10], a[11]),
                             pk2(a[12], a[13]), pk2(a[14], a[15]) };
                int sw = SWZ8(v);
                *(uint4*)(i1 + v * 16 + sw)       = p0;
                *(uint4*)(i1 + v * 16 + (8 - sw)) = p1;
            }
        }
        __syncthreads();

        // ---- conv2 d=3 ----
#pragma unroll
        for (int k = 0; k < 9; ++k) {
            if (k == 8 && wv >= 2) break;
            bf16x8 Ba = *(const bf16x8*)(pa2 + 1024 * k);
            bf16x8 Bb = *(const bf16x8*)(pb2 + 1024 * k);
            f32x4 acc = c2v;
            acc = __builtin_amdgcn_mfma_f32_16x16x32_bf16(W2a, Ba, acc, 0, 0, 0);
            acc = __builtin_amdgcn_mfma_f32_16x16x32_bf16(W2b, Bb, acc, 0, 0, 0);
            uint2 pq = { pk2(fmaxf(acc[0], 0.f), fmaxf(acc[1], 0.f)),
                         pk2(fmaxf(acc[2], 0.f), fmaxf(acc[3], 0.f)) };
            *(uint2*)(pw2 + 1024 * k) = pq;
        }
        __syncthreads();

        // ---- conv3 d=9 transposed -> s3 + norm ----
#pragma unroll
        for (int k = 0; k < 8; ++k) {
            bf16x8 Aa = *(const bf16x8*)(pa3 + 1024 * k);
            bf16x8 Ab = *(const bf16x8*)(pb3 + 1024 * k);
            f32x4 acc = c3v;
            acc = __builtin_amdgcn_mfma_f32_16x16x32_bf16(Aa, W3a, acc, 0, 0, 0);
            acc = __builtin_amdgcn_mfma_f32_16x16x32_bf16(Ab, W3b, acc, 0, 0, 0);
            int u4 = wv * 16 + 4 * lg + 64 * k;
            float v[4];
#pragma unroll
            for (int r = 0; r < 4; ++r) {
                float x = ((u4 + r) < Lv) ? fmaxf(acc[r], 0.f) : 0.f;
                v[r] = x;
                nstc += x * x;
            }
            uint2 pq = { pk2(v[0], v[1]), pk2(v[2], v[3]) };
            *(uint2*)(ps3 + 64 * k) = pq;
        }
        __syncthreads();
    }

    // ---- final dot (chunk 3) ----
#pragma unroll
    for (int kk = 0; kk < 4; ++kk) {
        bf16x8 Af = *(const bf16x8*)(pd + 32 * kk);
        dacc = __builtin_amdgcn_mfma_f32_16x16x32_bf16(Af, as_bf(bq[kk]), dacc, 0, 0, 0);
    }
    __syncthreads();   // all dot reads of s3 done before red (aliases smem head) is written

    // ---- cross-wave reduction in LDS ----
    nstc += __shfl_xor(nstc, 16);
    nstc += __shfl_xor(nstc, 32);
    float* red  = (float*)smem;            // 768 f32 = 3072B
    float* redn = (float*)(smem + 3072);   // 48 f32
    if (wv > 0) {
        *(f32x4*)(red + ((wv - 1) * 64 + lane) * 4) = dacc;
        if (lg == 0) redn[(wv - 1) * 16 + lm] = nstc;
    }
    __syncthreads();
    if (wv == 0) {
#pragma unroll
        for (int w = 0; w < 3; ++w) {
            f32x4 o = *(const f32x4*)(red + (w * 64 + lane) * 4);
#pragma unroll
            for (int r = 0; r < 4; ++r) dacc[r] += o[r];
        }
        int ob = bs * 4 + G;
        *(f32x4*)(dotp + (size_t)ob * 256 + lane * 4) = dacc;
        if (lg == 0)
            nstp[(size_t)ob * 16 + lm] = nstc + redn[lm] + redn[16 + lm] + redn[32 + lm];
    }
}

// =========== K5: reduce partials, cosine, linear head ===========
__global__ __launch_bounds__(256) void k_head(const float* __restrict__ dotp,
                                              const float* __restrict__ nstp,
                                              const float* __restrict__ nxp,
                                              const float* __restrict__ wlin,
                                              const float* __restrict__ blin,
                                              float* __restrict__ out) {
    int bs = blockIdx.x, tid = threadIdx.x;
    int b = bs >> 3;
    __shared__ float nxv[16];
    if (tid < 16) {
        float s = 0.f;
#pragma unroll
        for (int ch = 0; ch < 32; ++ch) s += nxp[((size_t)b * 16 + tid) * 32 + ch];
        nxv[tid] = fmaxf(sqrtf(s), EPS_);
    }
    __syncthreads();
    int i = 4 * (tid >> 6) + (tid & 3);
    int j = (tid >> 2) & 15;
    float dot = 0.f, ss = 0.f;
#pragma unroll
    for (int gw = 0; gw < 4; ++gw) {
        dot += dotp[(size_t)(bs * 4 + gw) * 256 + tid];
        ss  += nstp[(size_t)(bs * 4 + gw) * 16 + i];
    }
    float nstv = fmaxf(sqrtf(ss), EPS_);
    float val = dot / (nstv * nxv[j]) * wlin[i * 16 + j];
#pragma unroll
    for (int m = 32; m > 0; m >>= 1) val += __shfl_down(val, m, 64);
    __shared__ float rd[4];
    if ((tid & 63) == 0) rd[tid >> 6] = val;
    __syncthreads();
    if (tid == 0) out[bs] = rd[0] + rd[1] + rd[2] + rd[3] + blin[0];
}

extern "C" void kernel_launch(void* const* d_in, const int* in_sizes, int n_in,
                              void* d_out, int out_size, void* d_ws, size_t ws_size,
                              hipStream_t stream) {
    const float* eeg   = (const float*)d_in[0];
    const float* stim  = (const float*)d_in[1];
    const float* w_eeg = (const float*)d_in[2];
    const float* b_eeg = (const float*)d_in[3];
    const float* w_e1  = (const float*)d_in[4];
    const float* b_e1  = (const float*)d_in[5];
    const float* w_e2  = (const float*)d_in[6];
    const float* b_e2  = (const float*)d_in[7];
    const float* w_e3  = (const float*)d_in[8];
    const float* b_e3  = (const float*)d_in[9];
    const float* w_s1  = (const float*)d_in[10];
    const float* b_s1  = (const float*)d_in[11];
    const float* w_s2  = (const float*)d_in[12];
    const float* b_s2  = (const float*)d_in[13];
    const float* w_s3  = (const float*)d_in[14];
    const float* b_s3  = (const float*)d_in[15];
    const float* w_lin = (const float*)d_in[16];
    const float* b_lin = (const float*)d_in[17];

    unsigned char* ws = (unsigned char*)d_ws;
    unsigned short* x3b  = (unsigned short*)ws;                 // 16,728,064 B
    float*          nxp  = (float*)(ws + 16728064);             // 131,072 B
    float*          dotp = (float*)(ws + 16859136);             // 2,097,152 B
    float*          nstp = (float*)(ws + 25247744);             // 131,072 B
    unsigned short* x0b  = (unsigned short*)(ws + 25772032);    // 8,388,608 B
    unsigned short* wfE  = (unsigned short*)(ws + 34160640);    // 5,120 B
    unsigned short* wfS  = (unsigned short*)(ws + 34165760);    // 4,096 B
    float*          out  = (float*)d_out;

    k_eeg1x1<<<(B_ * T_) / 256, 256, 0, stream>>>(eeg, w_eeg, b_eeg, x0b,
                                                  w_e1, w_e2, w_e3, w_s2, w_s3, wfE, wfS);
    k_estack<<<dim3(32, B_), 256, 0, stream>>>(x0b, b_e1, b_e2, b_e3, wfE, x3b, nxp);
    k_stim<<<dim3(B_ * S_, 4), 256, 0, stream>>>(stim, w_s1, b_s1, b_s2, b_s3,
                                                 wfS, x3b, dotp, nstp);
    k_head<<<B_ * S_, 256, 0, stream>>>(dotp, nstp, nxp, w_lin, b_lin, out);
}